// Round 19
// baseline (87.732 us; speedup 1.0000x reference)
//
#include <hip/hip_runtime.h>
#include <hip/hip_bf16.h>

#define N_SUPPORT 32768
#define N_QUERY   16384
#define DIM       512
#define NCLS      32
#define NU        128
#define NBLK      (N_SUPPORT / 256)   // 128 histogram blocks

// workspace byte offsets (all 128B aligned)
#define OFF_IDX      0         // int[32768]
#define OFF_COUNT    131072    // int[32]
#define OFF_START    131200    // int[33]
#define OFF_M        131456    // float[32]
#define OFF_Z        131584    // float[32]
#define OFF_P2       131712    // float[32]
#define OFF_LOGIT    132096    // float[32768]
#define OFF_PRAW     263168    // float[32*512]
#define OFF_PROTO    328704    // float[32*512]
#define OFF_BHIST    394240    // int[128*32]
#define OFF_BOFFS    410624    // int[128*32]
#define OFF_VBF      458752    // short[32*8*128*64] bf16 V, chunked+swizzled (4 MB)
#define OFF_PBF      4653056   // short[2*32*512] proto hi/lo bf16 (128 KB)
#define OFF_INV      4718592   // int[32768] packed (pos<<3)|swz
#define OFF_XS       4849664   // short[(32768+32)*512] class-sorted bf16 X image (~33.6 MB)

typedef __attribute__((ext_vector_type(8))) short short8;
typedef __attribute__((ext_vector_type(4))) short short4v;
typedef __attribute__((ext_vector_type(4))) float f32x4;

typedef __attribute__((address_space(3))) unsigned int lds_u32;
typedef const __attribute__((address_space(1))) unsigned int glb_u32;

__device__ inline unsigned short f2bf(float f) {   // RNE f32 -> bf16
    unsigned int x = __builtin_bit_cast(unsigned int, f);
    unsigned int r = x + 0x7fffu + ((x >> 16) & 1u);
    return (unsigned short)(r >> 16);
}
__device__ inline float bf2f(unsigned short h) {
    unsigned int u = ((unsigned int)h) << 16;
    return __builtin_bit_cast(float, u);
}

__device__ inline short8 pack_bf8(float4 f0, float4 f1) {
    short8 pk;
    pk[0] = f2bf(f0.x); pk[1] = f2bf(f0.y); pk[2] = f2bf(f0.z); pk[3] = f2bf(f0.w);
    pk[4] = f2bf(f1.x); pk[5] = f2bf(f1.y); pk[6] = f2bf(f1.z); pk[7] = f2bf(f1.w);
    return pk;
}

// split 8 f32 into hi/lo bf16 planes (bf16x3 compensation: x ~= hi + lo)
__device__ inline void pack_hilo(float4 f0, float4 f1, short8& hi, short8& lo) {
    float v[8] = {f0.x, f0.y, f0.z, f0.w, f1.x, f1.y, f1.z, f1.w};
    #pragma unroll
    for (int i = 0; i < 8; i++) {
        unsigned short h = f2bf(v[i]);
        hi[i] = (short)h;
        lo[i] = (short)f2bf(v[i] - bf2f(h));
    }
}

// precast V to bf16 in the chunked+swizzled layout:
// Vbf[((k*8 + c)*128 + u)*64 + s*8 + j] = bf16(V[k][u][c*64 + (s^(u&7))*8 + j])
// Fused: blocks < NBLK also compute the per-block label histogram; also zero praw.
__global__ void k_vcast(const float* __restrict__ V, short* __restrict__ Vbf,
                        float* __restrict__ praw, const int* __restrict__ labels,
                        int* __restrict__ bhist) {
    __shared__ int h[NCLS];
    int tid = threadIdx.x;
    bool dohist = (blockIdx.x < NBLK);
    if (dohist) {
        if (tid < NCLS) h[tid] = 0;
        __syncthreads();
        atomicAdd(&h[labels[blockIdx.x * 256 + tid]], 1);
    }
    int i = blockIdx.x * 256 + tid;
    int ob = i * 4;                       // output short offset (4 shorts/thread)
    int j0  = ob & 7;                     // 0 or 4
    int s   = (ob >> 3) & 7;
    int u   = (ob >> 6) & 127;
    int c   = (ob >> 13) & 7;
    int k   = ob >> 16;
    int d   = c * 64 + ((s ^ (u & 7)) * 8) + j0;
    float4 f = *(const float4*)(V + ((size_t)(k * 128 + u) * DIM + d));
    short4v o;
    o[0] = f2bf(f.x); o[1] = f2bf(f.y); o[2] = f2bf(f.z); o[3] = f2bf(f.w);
    *(short4v*)(Vbf + (size_t)ob) = o;
    if (i < (NCLS * DIM) / 4) *(float4*)(praw + i * 4) = make_float4(0.f, 0.f, 0.f, 0.f);
    if (dohist) {
        __syncthreads();
        if (tid < NCLS) bhist[blockIdx.x * NCLS + tid] = h[tid];
    }
}

// phase B: single block. boffs[b][k] = sum_{b'<b} bhist[b'][k]; start/count per class.
__global__ void k_scan2(const int* __restrict__ bhist, int* __restrict__ boffs,
                        int* __restrict__ start, int* __restrict__ count) {
    __shared__ int tot[NCLS];
    int tid = threadIdx.x;
    if (tid < NCLS) {
        int s = 0;
        for (int b = 0; b < NBLK; b++) {
            boffs[b * NCLS + tid] = s;
            s += bhist[b * NCLS + tid];
        }
        tot[tid] = s;
    }
    __syncthreads();
    if (tid == 0) {
        int run = 0;
        for (int k = 0; k < NCLS; k++) {
            start[k] = run;
            count[k] = tot[k];
            run += tot[k];
        }
        start[NCLS] = run;
    }
}

// phase C: stable scatter. Also emits inv[n] = (pos<<3) | ((pos - start[l]) & 7).
__global__ void k_scatter(const int* __restrict__ labels, const int* __restrict__ boffs,
                          const int* __restrict__ start, int* __restrict__ idx_c,
                          int* __restrict__ inv) {
    __shared__ int whist[4][NCLS];
    int tid = threadIdx.x;
    int n = blockIdx.x * 256 + tid;
    int l = labels[n];
    int lane = tid & 63, wid = tid >> 6;
    unsigned long long mymask = 0ull;
    #pragma unroll
    for (int k = 0; k < NCLS; k++) {
        unsigned long long mk = __ballot(l == k);
        if (k == l) mymask = mk;
        if (lane == k) whist[wid][k] = __popcll(mk);
    }
    int rank = __popcll(mymask & ((1ull << lane) - 1ull));
    __syncthreads();
    int wbase = 0;
    for (int w = 0; w < wid; w++) wbase += whist[w][l];
    int pos = start[l] + boffs[blockIdx.x * NCLS + l] + wbase + rank;
    idx_c[pos] = n;
    inv[n] = (pos << 3) | ((pos - start[l]) & 7);
}

// gather/pack: read support in ORIGINAL order (contiguous 2KB/wave streams),
// convert to bf16, scatter-write each row's 1KB LDS-image into Xsorted.
__launch_bounds__(256, 1)
__global__ void k_gather(const float* __restrict__ support, const int* __restrict__ inv,
                         short* __restrict__ xs) {
    int t = threadIdx.x;
    int l = t & 63, wv = t >> 6;
    int rowbase = blockIdx.x * 64;
    #pragma unroll 4
    for (int i = 0; i < 16; i++) {
        int n = rowbase + wv + 4 * i;
        const float* src = support + (size_t)n * DIM + l * 8;
        float4 f0 = *(const float4*)src;
        float4 f1 = *(const float4*)(src + 4);
        int iv = inv[n];
        int pos = iv >> 3, swz = iv & 7;
        *(short8*)&xs[(size_t)pos * 512 + ((l ^ swz) * 8)] = pack_bf8(f0, f1);
    }
}

// per-class MFMA GEMM, MULTI-TILE PIPELINED (T3/T4): each block owns 4 tiles of
// 32 samples of class k. V[k] fragments in registers ONCE per block (kills 8x
// V re-reads). X tiles double-buffered via global_load_lds; loads for tile t+2
// issued while t+1's stay IN FLIGHT across both barriers (s_waitcnt vmcnt(8),
// never 0 until the last tile). This is the outstanding-loads fix for the
// rounds-6..18 ~40us invariant (per-block full-drain bursts -> 1.2 TB/s).
__launch_bounds__(256, 1)
__global__ void k_logits(const short* __restrict__ xs, const short* __restrict__ Vbf,
                         const float* __restrict__ w,
                         const int* __restrict__ start, const int* __restrict__ count,
                         float* __restrict__ logit_c) {
    int k = blockIdx.y;
    int cnt = count[k];
    int tb = blockIdx.x;                 // 0..15, owns tiles tb*4 .. tb*4+3
    int s0k = start[k];
    int t = threadIdx.x;

    __shared__ __align__(16) short Xb[2][32 * 512];   // 2 x 32 KB
    __shared__ float part[4][32];

    int l = t & 63, wv = t >> 6;
    int lo16 = l & 15, hi4 = l >> 4;

    // V: all 8 chunks' fragments, once per block (32 x short8 = 128 VGPR)
    const short* Vk = Vbf + (size_t)k * (8 * 128 * 64);
    short8 vreg[8][2][2];
    #pragma unroll
    for (int c = 0; c < 8; c++)
        #pragma unroll
        for (int ks = 0; ks < 2; ks++)
            #pragma unroll
            for (int nt = 0; nt < 2; nt++) {
                int u = wv * 32 + nt * 16 + lo16;
                int q = ks * 4 + hi4;
                vreg[c][ks][nt] = *(const short8*)(Vk + (size_t)c * 8192 + (size_t)u * 64 + ((q ^ (u & 7)) * 8));
            }

    float w0 = w[k * NU + wv * 32 + lo16];
    float w1 = w[k * NU + wv * 32 + 16 + lo16];

    // issue one tile's X image (32 KB linear): 8 x gload_lds 16B per thread.
    // Inactive tiles load tile base 0 (clamped) to keep the vmcnt FIFO uniform.
#define ISSUE(tt, buf) { int base_ = (tb * 4 + (tt)) * 32;                         \
        int cb_ = (base_ < cnt) ? base_ : 0;                                       \
        const short* src_ = xs + (size_t)(s0k + cb_) * 512;                        \
        _Pragma("unroll") for (int rep = 0; rep < 8; rep++) {                      \
            int u_ = t + 256 * rep;                                                \
            __builtin_amdgcn_global_load_lds((glb_u32*)(src_ + (size_t)u_ * 8),    \
                                             (lds_u32*)&Xb[buf][u_ * 8], 16, 0, 0);\
        } }

    ISSUE(0, 0);
    ISSUE(1, 1);

    #pragma unroll
    for (int tt = 0; tt < 4; tt++) {
        int cur = tt & 1;
        if (tt < 3) { asm volatile("s_waitcnt vmcnt(8)" ::: "memory"); }
        else        { asm volatile("s_waitcnt vmcnt(0)" ::: "memory"); }
        __builtin_amdgcn_s_barrier();    // tile tt's image visible everywhere

        int base = (tb * 4 + tt) * 32;
        bool active = (base < cnt);      // block-uniform
        if (active) {
            f32x4 acc[2][2];
            #pragma unroll
            for (int mt = 0; mt < 2; mt++)
                #pragma unroll
                for (int nt = 0; nt < 2; nt++) acc[mt][nt] = (f32x4){0.f, 0.f, 0.f, 0.f};
            #pragma unroll
            for (int c = 0; c < 8; c++)
                #pragma unroll
                for (int ks = 0; ks < 2; ks++) {
                    short8 a[2];
                    #pragma unroll
                    for (int mt = 0; mt < 2; mt++) {
                        int ar = mt * 16 + lo16;
                        int cu = c * 8 + ks * 4 + hi4;
                        a[mt] = *(short8*)&Xb[cur][ar * 512 + ((cu ^ (ar & 7)) * 8)];
                    }
                    #pragma unroll
                    for (int mt = 0; mt < 2; mt++)
                        #pragma unroll
                        for (int nt = 0; nt < 2; nt++)
                            acc[mt][nt] = __builtin_amdgcn_mfma_f32_16x16x32_bf16(a[mt], vreg[c][ks][nt], acc[mt][nt], 0, 0, 0);
                }
            // epilogue: tanh*w, shfl-reduce over 16 u-lanes, stage per-wave partials
            #pragma unroll
            for (int mt = 0; mt < 2; mt++) {
                #pragma unroll
                for (int r = 0; r < 4; r++) {
                    float val = tanhf(acc[mt][0][r]) * w0 + tanhf(acc[mt][1][r]) * w1;
                    val += __shfl_xor(val, 1);
                    val += __shfl_xor(val, 2);
                    val += __shfl_xor(val, 4);
                    val += __shfl_xor(val, 8);
                    if (lo16 == 0) part[wv][mt * 16 + hi4 * 4 + r] = val;
                }
            }
        }
        __builtin_amdgcn_s_barrier();    // all reads of Xb[cur] + part writes done
        if (active && t < 32) {
            int M = min(32, cnt - base);
            if (t < M)
                logit_c[s0k + base + t] = part[0][t] + part[1][t] + part[2][t] + part[3][t];
        }
        if (tt + 2 < 4) ISSUE(tt + 2, cur);   // refill the freed buffer; stays in flight
    }
#undef ISSUE
}

// per-class max and sum-exp (deterministic tree reduce)
__global__ void k_mz(const float* __restrict__ logit_c, const int* __restrict__ start,
                     const int* __restrict__ count, float* __restrict__ m, float* __restrict__ Z) {
    int k = blockIdx.x;
    int cnt = count[k], s0 = start[k];
    int tid = threadIdx.x;
    __shared__ float red[256];
    float mx = -1e30f;
    for (int i = tid; i < cnt; i += 256) mx = fmaxf(mx, logit_c[s0 + i]);
    red[tid] = mx; __syncthreads();
    for (int off = 128; off > 0; off >>= 1) {
        if (tid < off) red[tid] = fmaxf(red[tid], red[tid + off]);
        __syncthreads();
    }
    float mk = red[0];
    __syncthreads();
    float s = 0.f;
    for (int i = tid; i < cnt; i += 256) s += expf(logit_c[s0 + i] - mk);
    red[tid] = s; __syncthreads();
    for (int off = 128; off > 0; off >>= 1) {
        if (tid < off) red[tid] += red[tid + off];
        __syncthreads();
    }
    if (tid == 0) { m[k] = mk; Z[k] = red[0]; }
}

// weighted prototype accumulation: weights+indices staged once in LDS,
// 4-row explicit load pipeline, tile 64 -> 512 active blocks.
__launch_bounds__(512, 1)
__global__ void k_proto(const float* __restrict__ support, const int* __restrict__ idx_c,
                        const float* __restrict__ logit_c, const int* __restrict__ start,
                        const int* __restrict__ count, const float* __restrict__ m,
                        float* __restrict__ praw) {
    int k = blockIdx.y;
    int cnt = count[k];
    int base = blockIdx.x * 64;
    if (base >= cnt) return;
    int M = min(64, cnt - base);
    int s0 = start[k] + base;
    __shared__ float wts[64];
    __shared__ int sid[64];
    int t = threadIdx.x;
    if (t < 64) {
        sid[t] = idx_c[s0 + ((t < M) ? t : 0)];
        wts[t] = (t < M) ? expf(logit_c[s0 + t] - m[k]) : 0.f;
    }
    __syncthreads();
    int d = t;
    float a = 0.f;
    for (int s = 0; s < 64; s += 4) {
        float r0 = support[(size_t)sid[s + 0] * DIM + d];
        float r1 = support[(size_t)sid[s + 1] * DIM + d];
        float r2 = support[(size_t)sid[s + 2] * DIM + d];
        float r3 = support[(size_t)sid[s + 3] * DIM + d];
        a += wts[s] * r0 + wts[s + 1] * r1 + wts[s + 2] * r2 + wts[s + 3] * r3;
    }
    atomicAdd(&praw[k * DIM + d], a);
}

// normalize by Z, empty-class mean fallback, p2 = |proto|^2, and write the
// hi/lo bf16 proto planes in the chunked+swizzled layout k_dist's LDS wants.
__global__ void k_protonorm(const float* __restrict__ support, const float* __restrict__ praw,
                            const float* __restrict__ Z, const int* __restrict__ count,
                            float* __restrict__ proto, float* __restrict__ p2,
                            short* __restrict__ Pbf) {
    int k = blockIdx.x;
    int tid = threadIdx.x;
    int cnt = count[k];
    __shared__ float red[256];
    float pv[2];
    if (cnt > 0) {
        float inv = 1.f / Z[k];
        #pragma unroll
        for (int i = 0; i < 2; i++) pv[i] = praw[k * DIM + tid + i * 256] * inv;
    } else {
        #pragma unroll
        for (int i = 0; i < 2; i++) {
            int d = tid + i * 256;
            float s = 0.f;
            for (int n = 0; n < N_SUPPORT; n++) s += support[(size_t)n * DIM + d];
            pv[i] = s * (1.f / N_SUPPORT);
        }
    }
    float acc = 0.f;
    #pragma unroll
    for (int i = 0; i < 2; i++) {
        int d = tid + i * 256;
        proto[k * DIM + d] = pv[i];
        acc += pv[i] * pv[i];
        int c = d >> 6, off = d & 63, o = off >> 3, j = off & 7;
        int s = o ^ (k & 7);
        int pos = (c * 32 + k) * 64 + s * 8 + j;
        unsigned short hi = f2bf(pv[i]);
        Pbf[pos] = (short)hi;
        Pbf[NCLS * DIM + pos] = (short)f2bf(pv[i] - bf2f(hi));
    }
    red[tid] = acc; __syncthreads();
    for (int off = 128; off > 0; off >>= 1) {
        if (tid < off) red[tid] += red[tid + off];
        __syncthreads();
    }
    if (tid == 0) p2[k] = red[0];
}

// distances + log_softmax via MFMA bf16x3 (round-12 kernel verbatim — verified fast)
__launch_bounds__(256, 1)
__global__ void k_dist(const float* __restrict__ query, const short* __restrict__ Pbf,
                       const float* __restrict__ p2, float* __restrict__ out) {
    __shared__ __align__(16) short Ph[NCLS * DIM];      // 32 KB
    __shared__ __align__(16) short Pl[NCLS * DIM];      // 32 KB
    __shared__ __align__(16) short Qh[2][64 * 64];      // 2 x 8 KB
    __shared__ __align__(16) short Ql[2][64 * 64];      // 2 x 8 KB
    int t = threadIdx.x;
    int qbase = blockIdx.x * 64;
    int l = t & 63, wv = t >> 6;
    int lo16 = l & 15, hi4 = l >> 4;

    #pragma unroll
    for (int rep = 0; rep < 8; rep++) {
        int u = t + 256 * rep;
        ((short8*)Ph)[u] = ((const short8*)Pbf)[u];
        ((short8*)Pl)[u] = ((const short8*)(Pbf + NCLS * DIM))[u];
    }

    int qrow[2], qslot[2], qdst[2];
    const float* qsrc[2];
    #pragma unroll
    for (int rep = 0; rep < 2; rep++) {
        int u = t + 256 * rep;
        qrow[rep] = u >> 3; qslot[rep] = u & 7;
        qdst[rep] = qrow[rep] * 64 + ((qslot[rep] ^ (qrow[rep] & 7)) * 8);
        qsrc[rep] = query + (size_t)(qbase + qrow[rep]) * DIM + qslot[rep] * 8;
    }

    f32x4 acc[2];
    acc[0] = (f32x4){0.f, 0.f, 0.f, 0.f};
    acc[1] = (f32x4){0.f, 0.f, 0.f, 0.f};

    float4 qa[2][2], qb[2][2];
#define LOADQ(d, c) { _Pragma("unroll") for (int rep = 0; rep < 2; rep++) { \
        d[rep][0] = *(const float4*)(qsrc[rep] + (c) * 64);                 \
        d[rep][1] = *(const float4*)(qsrc[rep] + (c) * 64 + 4); } }
#define WRITEQ(buf, d) { _Pragma("unroll") for (int rep = 0; rep < 2; rep++) { \
        short8 hi8, lo8;                                                        \
        pack_hilo(d[rep][0], d[rep][1], hi8, lo8);                              \
        *(short8*)&Qh[buf][qdst[rep]] = hi8;                                    \
        *(short8*)&Ql[buf][qdst[rep]] = lo8; } }

    LOADQ(qa, 0);
    LOADQ(qb, 1);
    WRITEQ(0, qa);

    for (int c = 0; c < 8; ++c) {
        int cur = c & 1;
        __syncthreads();
        if (c + 2 < 8) {
            if (cur == 0) { LOADQ(qa, c + 2); }
            else          { LOADQ(qb, c + 2); }
        }
        #pragma unroll
        for (int ks = 0; ks < 2; ks++) {
            int arow = wv * 16 + lo16;
            int asw = ((ks * 4 + hi4) ^ (arow & 7)) * 8;
            short8 ah = *(short8*)&Qh[cur][arow * 64 + asw];
            short8 al = *(short8*)&Ql[cur][arow * 64 + asw];
            #pragma unroll
            for (int nt = 0; nt < 2; nt++) {
                int brow = nt * 16 + lo16;
                int pos = (c * 32 + brow) * 64 + (((ks * 4 + hi4) ^ (brow & 7)) * 8);
                short8 bh = *(short8*)&Ph[pos];
                short8 bl = *(short8*)&Pl[pos];
                acc[nt] = __builtin_amdgcn_mfma_f32_16x16x32_bf16(ah, bh, acc[nt], 0, 0, 0);
                acc[nt] = __builtin_amdgcn_mfma_f32_16x16x32_bf16(ah, bl, acc[nt], 0, 0, 0);
                acc[nt] = __builtin_amdgcn_mfma_f32_16x16x32_bf16(al, bh, acc[nt], 0, 0, 0);
            }
        }
        if (c < 7) {
            if (cur == 0) { WRITEQ(1, qb); }
            else          { WRITEQ(0, qa); }
        }
    }
#undef LOADQ
#undef WRITEQ

    float p2v0 = p2[lo16];
    float p2v1 = p2[16 + lo16];
    #pragma unroll
    for (int r = 0; r < 4; r++) {
        float l0 = 2.f * acc[0][r] - p2v0;
        float l1 = 2.f * acc[1][r] - p2v1;
        float mx = fmaxf(l0, l1);
        mx = fmaxf(mx, __shfl_xor(mx, 1));
        mx = fmaxf(mx, __shfl_xor(mx, 2));
        mx = fmaxf(mx, __shfl_xor(mx, 4));
        mx = fmaxf(mx, __shfl_xor(mx, 8));
        float s = expf(l0 - mx) + expf(l1 - mx);
        s += __shfl_xor(s, 1);
        s += __shfl_xor(s, 2);
        s += __shfl_xor(s, 4);
        s += __shfl_xor(s, 8);
        float lse = mx + logf(s);
        int q = qbase + wv * 16 + hi4 * 4 + r;
        out[(size_t)q * NCLS + lo16] = l0 - lse;
        out[(size_t)q * NCLS + 16 + lo16] = l1 - lse;
    }
}

extern "C" void kernel_launch(void* const* d_in, const int* in_sizes, int n_in,
                              void* d_out, int out_size, void* d_ws, size_t ws_size,
                              hipStream_t stream) {
    const float* query   = (const float*)d_in[0];
    const float* support = (const float*)d_in[1];
    const int*   labels  = (const int*)d_in[2];
    const float* V       = (const float*)d_in[3];
    const float* w       = (const float*)d_in[4];
    float* out = (float*)d_out;
    char* ws = (char*)d_ws;

    int*   idx_c   = (int*)(ws + OFF_IDX);
    int*   count   = (int*)(ws + OFF_COUNT);
    int*   start   = (int*)(ws + OFF_START);
    float* m       = (float*)(ws + OFF_M);
    float* Z       = (float*)(ws + OFF_Z);
    float* p2      = (float*)(ws + OFF_P2);
    float* logit_c = (float*)(ws + OFF_LOGIT);
    float* praw    = (float*)(ws + OFF_PRAW);
    float* proto   = (float*)(ws + OFF_PROTO);
    int*   bhist   = (int*)(ws + OFF_BHIST);
    int*   boffs   = (int*)(ws + OFF_BOFFS);
    short* vbf     = (short*)(ws + OFF_VBF);
    short* pbf     = (short*)(ws + OFF_PBF);
    int*   inv     = (int*)(ws + OFF_INV);
    short* xsorted = (short*)(ws + OFF_XS);

    hipLaunchKernelGGL(k_vcast, dim3((NCLS * NU * DIM) / 1024), dim3(256), 0, stream,
                       V, vbf, praw, labels, bhist);
    hipLaunchKernelGGL(k_scan2, dim3(1), dim3(64), 0, stream, bhist, boffs, start, count);
    hipLaunchKernelGGL(k_scatter, dim3(NBLK), dim3(256), 0, stream, labels, boffs, start, idx_c, inv);
    hipLaunchKernelGGL(k_gather, dim3(N_SUPPORT / 64), dim3(256), 0, stream, support, inv, xsorted);
    // 16 x-blocks x 4 tiles of 32 = 64 tiles/class (covers counts up to 2048)
    hipLaunchKernelGGL(k_logits, dim3(16, NCLS), dim3(256), 0, stream,
                       xsorted, vbf, w, start, count, logit_c);
    hipLaunchKernelGGL(k_mz, dim3(NCLS), dim3(256), 0, stream, logit_c, start, count, m, Z);
    hipLaunchKernelGGL(k_proto, dim3(32, NCLS), dim3(512), 0, stream,
                       support, idx_c, logit_c, start, count, m, praw);
    hipLaunchKernelGGL(k_protonorm, dim3(NCLS), dim3(256), 0, stream,
                       support, praw, Z, count, proto, p2, pbf);
    hipLaunchKernelGGL(k_dist, dim3(N_QUERY / 64), dim3(256), 0, stream, query, pbf, p2, out);
}

// Round 20
// 70.544 us; speedup vs baseline: 1.2436x; 1.2436x over previous
//
#include <hip/hip_runtime.h>
#include <hip/hip_bf16.h>

#define N_SUPPORT 32768
#define N_QUERY   16384
#define DIM       512
#define NCLS      32
#define NU        128
#define NBLK      (N_SUPPORT / 256)   // 128 histogram blocks

// workspace byte offsets (all 128B aligned)
#define OFF_IDX      0         // int[32768]
#define OFF_COUNT    131072    // int[32]
#define OFF_START    131200    // int[33]
#define OFF_M        131456    // float[32]
#define OFF_Z        131584    // float[32]
#define OFF_P2       131712    // float[32]
#define OFF_LOGIT    132096    // float[32768]
#define OFF_PRAW     263168    // float[32*512]
#define OFF_PROTO    328704    // float[32*512]
#define OFF_BHIST    394240    // int[128*32]
#define OFF_BOFFS    410624    // int[128*32]
#define OFF_VBF      458752    // short[32*8*128*64] bf16 V, chunked+swizzled (4 MB)
#define OFF_PBF      4653056   // short[2*32*512] proto hi/lo bf16, chunked+swizzled (128 KB)

typedef __attribute__((ext_vector_type(8))) short short8;
typedef __attribute__((ext_vector_type(4))) short short4v;
typedef __attribute__((ext_vector_type(4))) float f32x4;

__device__ inline unsigned short f2bf(float f) {   // RNE f32 -> bf16
    unsigned int x = __builtin_bit_cast(unsigned int, f);
    unsigned int r = x + 0x7fffu + ((x >> 16) & 1u);
    return (unsigned short)(r >> 16);
}
__device__ inline float bf2f(unsigned short h) {
    unsigned int u = ((unsigned int)h) << 16;
    return __builtin_bit_cast(float, u);
}

__device__ inline short8 pack_bf8(float4 f0, float4 f1) {
    short8 pk;
    pk[0] = f2bf(f0.x); pk[1] = f2bf(f0.y); pk[2] = f2bf(f0.z); pk[3] = f2bf(f0.w);
    pk[4] = f2bf(f1.x); pk[5] = f2bf(f1.y); pk[6] = f2bf(f1.z); pk[7] = f2bf(f1.w);
    return pk;
}

// split 8 f32 into hi/lo bf16 planes (bf16x3 compensation: x ~= hi + lo)
__device__ inline void pack_hilo(float4 f0, float4 f1, short8& hi, short8& lo) {
    float v[8] = {f0.x, f0.y, f0.z, f0.w, f1.x, f1.y, f1.z, f1.w};
    #pragma unroll
    for (int i = 0; i < 8; i++) {
        unsigned short h = f2bf(v[i]);
        hi[i] = (short)h;
        lo[i] = (short)f2bf(v[i] - bf2f(h));
    }
}

// precast V to bf16 in the chunked+swizzled layout k_logits' LDS wants:
// Vbf[((k*8 + c)*128 + u)*64 + s*8 + j] = bf16(V[k][u][c*64 + (s^(u&7))*8 + j])
// Fused: blocks < NBLK also compute the per-block label histogram; also zero praw.
__global__ void k_vcast(const float* __restrict__ V, short* __restrict__ Vbf,
                        float* __restrict__ praw, const int* __restrict__ labels,
                        int* __restrict__ bhist) {
    __shared__ int h[NCLS];
    int tid = threadIdx.x;
    bool dohist = (blockIdx.x < NBLK);
    if (dohist) {
        if (tid < NCLS) h[tid] = 0;
        __syncthreads();
        atomicAdd(&h[labels[blockIdx.x * 256 + tid]], 1);
    }
    int i = blockIdx.x * 256 + tid;
    int ob = i * 4;                       // output short offset (4 shorts/thread)
    int j0  = ob & 7;                     // 0 or 4
    int s   = (ob >> 3) & 7;
    int u   = (ob >> 6) & 127;
    int c   = (ob >> 13) & 7;
    int k   = ob >> 16;
    int d   = c * 64 + ((s ^ (u & 7)) * 8) + j0;
    float4 f = *(const float4*)(V + ((size_t)(k * 128 + u) * DIM + d));
    short4v o;
    o[0] = f2bf(f.x); o[1] = f2bf(f.y); o[2] = f2bf(f.z); o[3] = f2bf(f.w);
    *(short4v*)(Vbf + (size_t)ob) = o;
    if (i < (NCLS * DIM) / 4) *(float4*)(praw + i * 4) = make_float4(0.f, 0.f, 0.f, 0.f);
    if (dohist) {
        __syncthreads();
        if (tid < NCLS) bhist[blockIdx.x * NCLS + tid] = h[tid];
    }
}

// phase B: single block. boffs[b][k] = sum_{b'<b} bhist[b'][k]; start/count per class.
__global__ void k_scan2(const int* __restrict__ bhist, int* __restrict__ boffs,
                        int* __restrict__ start, int* __restrict__ count) {
    __shared__ int tot[NCLS];
    int tid = threadIdx.x;
    if (tid < NCLS) {
        int s = 0;
        for (int b = 0; b < NBLK; b++) {
            boffs[b * NCLS + tid] = s;
            s += bhist[b * NCLS + tid];
        }
        tot[tid] = s;
    }
    __syncthreads();
    if (tid == 0) {
        int run = 0;
        for (int k = 0; k < NCLS; k++) {
            start[k] = run;
            count[k] = tot[k];
            run += tot[k];
        }
        start[NCLS] = run;
    }
}

// phase C: stable scatter. rank within wave via per-class ballot; across waves via LDS hist.
__global__ void k_scatter(const int* __restrict__ labels, const int* __restrict__ boffs,
                          const int* __restrict__ start, int* __restrict__ idx_c) {
    __shared__ int whist[4][NCLS];
    int tid = threadIdx.x;
    int n = blockIdx.x * 256 + tid;
    int l = labels[n];
    int lane = tid & 63, wid = tid >> 6;
    unsigned long long mymask = 0ull;
    #pragma unroll
    for (int k = 0; k < NCLS; k++) {
        unsigned long long mk = __ballot(l == k);
        if (k == l) mymask = mk;
        if (lane == k) whist[wid][k] = __popcll(mk);
    }
    int rank = __popcll(mymask & ((1ull << lane) - 1ull));
    __syncthreads();
    int wbase = 0;
    for (int w = 0; w < wid; w++) wbase += whist[w][l];
    idx_c[start[l] + boffs[blockIdx.x * NCLS + l] + wbase + rank] = n;
}

// per-class MFMA GEMM: P = X(64x512).V^T(512x128) bf16/f32acc;
// logit[n] = sum_u tanh(P[n,u])*w[k,u].
// 8 waves, M=64 tile, 8 MFMA/chunk/wave. 3-deep register-set rotation with raw
// s_barrier + lgkmcnt(0) (round-12 configuration — best measured, 39.4 us).
__launch_bounds__(512, 1)
__global__ void k_logits(const float* __restrict__ support, const short* __restrict__ Vbf,
                         const float* __restrict__ w, const int* __restrict__ idx_c,
                         const int* __restrict__ start, const int* __restrict__ count,
                         float* __restrict__ logit_c) {
    int k = blockIdx.y;
    int cnt = count[k];
    int base = blockIdx.x * 64;
    if (base >= cnt) return;
    int M = min(64, cnt - base);
    int s0 = start[k] + base;
    int t = threadIdx.x;

    __shared__ __align__(16) short Xs[2][64 * 64];    // 2 x 8 KB
    __shared__ __align__(16) short Vs[2][128 * 64];   // 2 x 16 KB
    __shared__ float part[8][64];                     // 2 KB
    __shared__ int sidx[64];
    if (t < 64) sidx[t] = idx_c[s0 + ((t < M) ? t : 0)];
    __syncthreads();

    int l = t & 63, wv = t >> 6;
    int lo16 = l & 15, hi4 = l >> 4;

    // X staging: 64 rows x 8 slots = 512 units, 1/thread
    int xrow = t >> 3, xslot = t & 7;
    int xdst = xrow * 64 + ((xslot ^ (xrow & 7)) * 8);
    const float* xsrc = support + (size_t)sidx[xrow] * DIM + xslot * 8;
    const short* Vkc = Vbf + (size_t)k * (8 * 128 * 64);   // chunk c at +c*8192

    f32x4 acc[4];
    #pragma unroll
    for (int mt = 0; mt < 4; mt++) acc[mt] = (f32x4){0.f, 0.f, 0.f, 0.f};

    // three prefetch register sets
    float4 xa0, xa1, xb0, xb1, xc0, xc1;
    short8 va[2], vb[2], vc[2];

#define LOADX(d0, d1, c) { d0 = *(const float4*)(xsrc + (c) * 64); \
                           d1 = *(const float4*)(xsrc + (c) * 64 + 4); }
#define LOADV(dst, c) { _Pragma("unroll") for (int rep = 0; rep < 2; rep++)   \
        dst[rep] = *(const short8*)(Vkc + (size_t)(c) * 8192 + (size_t)(t + 512 * rep) * 8); }
#define WRITEB(buf, x0, x1, vs) { *(short8*)&Xs[buf][xdst] = pack_bf8(x0, x1); \
        _Pragma("unroll") for (int rep = 0; rep < 2; rep++)                    \
        *(short8*)&Vs[buf][(t + 512 * rep) * 8] = vs[rep]; }
#define MFMA_CHUNK(cur) { _Pragma("unroll")                                       \
    for (int ks = 0; ks < 2; ks++) {                                              \
        short8 a[4], b;                                                           \
        _Pragma("unroll")                                                         \
        for (int mt = 0; mt < 4; mt++) {                                          \
            int ar = mt * 16 + lo16;                                              \
            a[mt] = *(short8*)&Xs[cur][ar * 64 + (((ks * 4 + hi4) ^ (ar & 7)) * 8)]; \
        }                                                                         \
        int vr = wv * 16 + lo16;                                                  \
        b = *(short8*)&Vs[cur][vr * 64 + (((ks * 4 + hi4) ^ (vr & 7)) * 8)];      \
        _Pragma("unroll")                                                         \
        for (int mt = 0; mt < 4; mt++)                                            \
            acc[mt] = __builtin_amdgcn_mfma_f32_16x16x32_bf16(a[mt], b, acc[mt], 0, 0, 0); \
    } }
#define BAR() { asm volatile("s_waitcnt lgkmcnt(0)" ::: "memory"); __builtin_amdgcn_s_barrier(); }

    // prologue: 3 sets in flight
    LOADX(xa0, xa1, 0); LOADV(va, 0);
    LOADX(xb0, xb1, 1); LOADV(vb, 1);
    LOADX(xc0, xc1, 2); LOADV(vc, 2);
    WRITEB(0, xa0, xa1, va);

    // c=0
    BAR(); LOADX(xa0, xa1, 3); LOADV(va, 3); MFMA_CHUNK(0); WRITEB(1, xb0, xb1, vb);
    // c=1
    BAR(); LOADX(xb0, xb1, 4); LOADV(vb, 4); MFMA_CHUNK(1); WRITEB(0, xc0, xc1, vc);
    // c=2
    BAR(); LOADX(xc0, xc1, 5); LOADV(vc, 5); MFMA_CHUNK(0); WRITEB(1, xa0, xa1, va);
    // c=3
    BAR(); LOADX(xa0, xa1, 6); LOADV(va, 6); MFMA_CHUNK(1); WRITEB(0, xb0, xb1, vb);
    // c=4
    BAR(); LOADX(xb0, xb1, 7); LOADV(vb, 7); MFMA_CHUNK(0); WRITEB(1, xc0, xc1, vc);
    // c=5
    BAR(); MFMA_CHUNK(1); WRITEB(0, xa0, xa1, va);
    // c=6
    BAR(); MFMA_CHUNK(0); WRITEB(1, xb0, xb1, vb);
    // c=7
    BAR(); MFMA_CHUNK(1);

#undef LOADX
#undef LOADV
#undef WRITEB
#undef MFMA_CHUNK
#undef BAR

    // epilogue: tanh * w, reduce over this wave's 16 u-cols, then across 8 waves.
    // D layout: row=(l>>4)*4+r, col=l&15 (verified rounds 5-19).
    float wval = w[k * NU + wv * 16 + lo16];
    #pragma unroll
    for (int mt = 0; mt < 4; mt++) {
        #pragma unroll
        for (int r = 0; r < 4; r++) {
            float val = tanhf(acc[mt][r]) * wval;
            val += __shfl_xor(val, 1);
            val += __shfl_xor(val, 2);
            val += __shfl_xor(val, 4);
            val += __shfl_xor(val, 8);
            if (lo16 == 0) part[wv][mt * 16 + hi4 * 4 + r] = val;
        }
    }
    __syncthreads();
    if (t < 64 && t < M) {
        float s = 0.f;
        #pragma unroll
        for (int wq = 0; wq < 8; wq++) s += part[wq][t];
        logit_c[s0 + t] = s;
    }
}

// per-class max and sum-exp (deterministic tree reduce)
__global__ void k_mz(const float* __restrict__ logit_c, const int* __restrict__ start,
                     const int* __restrict__ count, float* __restrict__ m, float* __restrict__ Z) {
    int k = blockIdx.x;
    int cnt = count[k], s0 = start[k];
    int tid = threadIdx.x;
    __shared__ float red[256];
    float mx = -1e30f;
    for (int i = tid; i < cnt; i += 256) mx = fmaxf(mx, logit_c[s0 + i]);
    red[tid] = mx; __syncthreads();
    for (int off = 128; off > 0; off >>= 1) {
        if (tid < off) red[tid] = fmaxf(red[tid], red[tid + off]);
        __syncthreads();
    }
    float mk = red[0];
    __syncthreads();
    float s = 0.f;
    for (int i = tid; i < cnt; i += 256) s += expf(logit_c[s0 + i] - mk);
    red[tid] = s; __syncthreads();
    for (int off = 128; off > 0; off >>= 1) {
        if (tid < off) red[tid] += red[tid + off];
        __syncthreads();
    }
    if (tid == 0) { m[k] = mk; Z[k] = red[0]; }
}

// weighted prototype accumulation: weights+indices staged once in LDS,
// 4-row explicit load pipeline, tile 64 -> 512 active blocks.
__launch_bounds__(512, 1)
__global__ void k_proto(const float* __restrict__ support, const int* __restrict__ idx_c,
                        const float* __restrict__ logit_c, const int* __restrict__ start,
                        const int* __restrict__ count, const float* __restrict__ m,
                        float* __restrict__ praw) {
    int k = blockIdx.y;
    int cnt = count[k];
    int base = blockIdx.x * 64;
    if (base >= cnt) return;
    int M = min(64, cnt - base);
    int s0 = start[k] + base;
    __shared__ float wts[64];
    __shared__ int sid[64];
    int t = threadIdx.x;
    if (t < 64) {
        sid[t] = idx_c[s0 + ((t < M) ? t : 0)];
        wts[t] = (t < M) ? expf(logit_c[s0 + t] - m[k]) : 0.f;
    }
    __syncthreads();
    int d = t;
    float a = 0.f;
    for (int s = 0; s < 64; s += 4) {
        float r0 = support[(size_t)sid[s + 0] * DIM + d];
        float r1 = support[(size_t)sid[s + 1] * DIM + d];
        float r2 = support[(size_t)sid[s + 2] * DIM + d];
        float r3 = support[(size_t)sid[s + 3] * DIM + d];
        a += wts[s] * r0 + wts[s + 1] * r1 + wts[s + 2] * r2 + wts[s + 3] * r3;
    }
    atomicAdd(&praw[k * DIM + d], a);
}

// normalize by Z, empty-class mean fallback, p2 = |proto|^2, and write the
// hi/lo bf16 proto planes in the chunked+swizzled layout k_dist's LDS wants:
// Pbf[plane][(c*32 + k)*64 + s*8 + j] = plane(proto[k][c*64 + (s^(k&7))*8 + j])
__global__ void k_protonorm(const float* __restrict__ support, const float* __restrict__ praw,
                            const float* __restrict__ Z, const int* __restrict__ count,
                            float* __restrict__ proto, float* __restrict__ p2,
                            short* __restrict__ Pbf) {
    int k = blockIdx.x;
    int tid = threadIdx.x;
    int cnt = count[k];
    __shared__ float red[256];
    float pv[2];
    if (cnt > 0) {
        float inv = 1.f / Z[k];
        #pragma unroll
        for (int i = 0; i < 2; i++) pv[i] = praw[k * DIM + tid + i * 256] * inv;
    } else {
        #pragma unroll
        for (int i = 0; i < 2; i++) {
            int d = tid + i * 256;
            float s = 0.f;
            for (int n = 0; n < N_SUPPORT; n++) s += support[(size_t)n * DIM + d];
            pv[i] = s * (1.f / N_SUPPORT);
        }
    }
    float acc = 0.f;
    #pragma unroll
    for (int i = 0; i < 2; i++) {
        int d = tid + i * 256;
        proto[k * DIM + d] = pv[i];
        acc += pv[i] * pv[i];
        // swizzled bf16 hi/lo write
        int c = d >> 6, off = d & 63, o = off >> 3, j = off & 7;
        int s = o ^ (k & 7);
        int pos = (c * 32 + k) * 64 + s * 8 + j;
        unsigned short hi = f2bf(pv[i]);
        Pbf[pos] = (short)hi;
        Pbf[NCLS * DIM + pos] = (short)f2bf(pv[i] - bf2f(hi));
    }
    red[tid] = acc; __syncthreads();
    for (int off = 128; off > 0; off >>= 1) {
        if (tid < off) red[tid] += red[tid + off];
        __syncthreads();
    }
    if (tid == 0) p2[k] = red[0];
}

// distances + log_softmax via MFMA bf16x3 (hi/lo split: dot = Ah.Bh + Ah.Bl + Al.Bh,
// residual ~2^-18 -> f32-grade). Block: 64 queries x 32 classes, 4 waves; wave wv
// owns queries wv*16..+15, both 16-class N-tiles. P planes resident in LDS (64 KB),
// Q hi/lo double-buffered (32 KB). Softmax fully in-register via shfl_xor.
__launch_bounds__(256, 1)
__global__ void k_dist(const float* __restrict__ query, const short* __restrict__ Pbf,
                       const float* __restrict__ p2, float* __restrict__ out) {
    __shared__ __align__(16) short Ph[NCLS * DIM];      // 32 KB
    __shared__ __align__(16) short Pl[NCLS * DIM];      // 32 KB
    __shared__ __align__(16) short Qh[2][64 * 64];      // 2 x 8 KB
    __shared__ __align__(16) short Ql[2][64 * 64];      // 2 x 8 KB
    int t = threadIdx.x;
    int qbase = blockIdx.x * 64;
    int l = t & 63, wv = t >> 6;
    int lo16 = l & 15, hi4 = l >> 4;

    // stage P planes once: 2048 short8 units/plane over 256 thr = 8 units each
    #pragma unroll
    for (int rep = 0; rep < 8; rep++) {
        int u = t + 256 * rep;
        ((short8*)Ph)[u] = ((const short8*)Pbf)[u];
        ((short8*)Pl)[u] = ((const short8*)(Pbf + NCLS * DIM))[u];
    }

    // Q staging: 512 units (64 rows x 8 slots of 8 floats), 2/thread
    int qrow[2], qslot[2], qdst[2];
    const float* qsrc[2];
    #pragma unroll
    for (int rep = 0; rep < 2; rep++) {
        int u = t + 256 * rep;
        qrow[rep] = u >> 3; qslot[rep] = u & 7;
        qdst[rep] = qrow[rep] * 64 + ((qslot[rep] ^ (qrow[rep] & 7)) * 8);
        qsrc[rep] = query + (size_t)(qbase + qrow[rep]) * DIM + qslot[rep] * 8;
    }

    f32x4 acc[2];
    acc[0] = (f32x4){0.f, 0.f, 0.f, 0.f};
    acc[1] = (f32x4){0.f, 0.f, 0.f, 0.f};

    float4 qa[2][2], qb[2][2];
#define LOADQ(d, c) { _Pragma("unroll") for (int rep = 0; rep < 2; rep++) { \
        d[rep][0] = *(const float4*)(qsrc[rep] + (c) * 64);                 \
        d[rep][1] = *(const float4*)(qsrc[rep] + (c) * 64 + 4); } }
#define WRITEQ(buf, d) { _Pragma("unroll") for (int rep = 0; rep < 2; rep++) { \
        short8 hi8, lo8;                                                        \
        pack_hilo(d[rep][0], d[rep][1], hi8, lo8);                              \
        *(short8*)&Qh[buf][qdst[rep]] = hi8;                                    \
        *(short8*)&Ql[buf][qdst[rep]] = lo8; } }

    LOADQ(qa, 0);
    LOADQ(qb, 1);
    WRITEQ(0, qa);

    for (int c = 0; c < 8; ++c) {
        int cur = c & 1;
        __syncthreads();                // buf[cur] (+ P planes on c==0) visible
        if (c + 2 < 8) {                // reload the consumed set 2 chunks ahead
            if (cur == 0) { LOADQ(qa, c + 2); }
            else          { LOADQ(qb, c + 2); }
        }
        #pragma unroll
        for (int ks = 0; ks < 2; ks++) {
            int arow = wv * 16 + lo16;
            int asw = ((ks * 4 + hi4) ^ (arow & 7)) * 8;
            short8 ah = *(short8*)&Qh[cur][arow * 64 + asw];
            short8 al = *(short8*)&Ql[cur][arow * 64 + asw];
            #pragma unroll
            for (int nt = 0; nt < 2; nt++) {
                int brow = nt * 16 + lo16;
                int pos = (c * 32 + brow) * 64 + (((ks * 4 + hi4) ^ (brow & 7)) * 8);
                short8 bh = *(short8*)&Ph[pos];
                short8 bl = *(short8*)&Pl[pos];
                acc[nt] = __builtin_amdgcn_mfma_f32_16x16x32_bf16(ah, bh, acc[nt], 0, 0, 0);
                acc[nt] = __builtin_amdgcn_mfma_f32_16x16x32_bf16(ah, bl, acc[nt], 0, 0, 0);
                acc[nt] = __builtin_amdgcn_mfma_f32_16x16x32_bf16(al, bh, acc[nt], 0, 0, 0);
            }
        }
        if (c < 7) {
            if (cur == 0) { WRITEQ(1, qb); }
            else          { WRITEQ(0, qa); }
        }
    }
#undef LOADQ
#undef WRITEQ

    // epilogue: logits + in-register log_softmax.
    // D layout: row=(l>>4)*4+r (query within wave tile), col=l&15 (class within N-tile).
    float p2v0 = p2[lo16];
    float p2v1 = p2[16 + lo16];
    #pragma unroll
    for (int r = 0; r < 4; r++) {
        float l0 = 2.f * acc[0][r] - p2v0;
        float l1 = 2.f * acc[1][r] - p2v1;
        float mx = fmaxf(l0, l1);
        mx = fmaxf(mx, __shfl_xor(mx, 1));
        mx = fmaxf(mx, __shfl_xor(mx, 2));
        mx = fmaxf(mx, __shfl_xor(mx, 4));
        mx = fmaxf(mx, __shfl_xor(mx, 8));
        float s = expf(l0 - mx) + expf(l1 - mx);
        s += __shfl_xor(s, 1);
        s += __shfl_xor(s, 2);
        s += __shfl_xor(s, 4);
        s += __shfl_xor(s, 8);
        float lse = mx + logf(s);
        int q = qbase + wv * 16 + hi4 * 4 + r;
        out[(size_t)q * NCLS + lo16] = l0 - lse;
        out[(size_t)q * NCLS + 16 + lo16] = l1 - lse;
    }
}

extern "C" void kernel_launch(void* const* d_in, const int* in_sizes, int n_in,
                              void* d_out, int out_size, void* d_ws, size_t ws_size,
                              hipStream_t stream) {
    const float* query   = (const float*)d_in[0];
    const float* support = (const float*)d_in[1];
    const int*   labels  = (const int*)d_in[2];
    const float* V       = (const float*)d_in[3];
    const float* w       = (const float*)d_in[4];
    float* out = (float*)d_out;
    char* ws = (char*)d_ws;

    int*   idx_c   = (int*)(ws + OFF_IDX);
    int*   count   = (int*)(ws + OFF_COUNT);
    int*   start   = (int*)(ws + OFF_START);
    float* m       = (float*)(ws + OFF_M);
    float* Z       = (float*)(ws + OFF_Z);
    float* p2      = (float*)(ws + OFF_P2);
    float* logit_c = (float*)(ws + OFF_LOGIT);
    float* praw    = (float*)(ws + OFF_PRAW);
    float* proto   = (float*)(ws + OFF_PROTO);
    int*   bhist   = (int*)(ws + OFF_BHIST);
    int*   boffs   = (int*)(ws + OFF_BOFFS);
    short* vbf     = (short*)(ws + OFF_VBF);
    short* pbf     = (short*)(ws + OFF_PBF);

    hipLaunchKernelGGL(k_vcast, dim3((NCLS * NU * DIM) / 1024), dim3(256), 0, stream,
                       V, vbf, praw, labels, bhist);
    hipLaunchKernelGGL(k_scan2, dim3(1), dim3(64), 0, stream, bhist, boffs, start, count);
    hipLaunchKernelGGL(k_scatter, dim3(NBLK), dim3(256), 0, stream, labels, boffs, start, idx_c);
    // 32 sample-tiles of 64 covers counts up to 2048 (expected ~1024 +/- 31)
    hipLaunchKernelGGL(k_logits, dim3(32, NCLS), dim3(512), 0, stream,
                       support, vbf, w, idx_c, start, count, logit_c);
    hipLaunchKernelGGL(k_mz, dim3(NCLS), dim3(256), 0, stream, logit_c, start, count, m, Z);
    hipLaunchKernelGGL(k_proto, dim3(32, NCLS), dim3(512), 0, stream,
                       support, idx_c, logit_c, start, count, m, praw);
    hipLaunchKernelGGL(k_protonorm, dim3(NCLS), dim3(256), 0, stream,
                       support, praw, Z, count, proto, p2, pbf);
    hipLaunchKernelGGL(k_dist, dim3(N_QUERY / 64), dim3(256), 0, stream, query, pbf, p2, out);
}